// Round 15
// baseline (159036.292 us; speedup 1.0000x reference)
//
#include <hip/hip_runtime.h>

typedef unsigned short u16;
typedef unsigned int   u32;
typedef _Float16 v8hf __attribute__((ext_vector_type(8)));
typedef float  f32x4 __attribute__((ext_vector_type(4)));

// ---------------- problem constants ----------------
static constexpr int B_   = 2048;
static constexpr int T_   = 64;
static constexpr int D_   = 64;
static constexpr int H_   = 256;
static constexpr int NL_  = 10;
static constexpr int FUT_ = 96;
static constexpr int NBLK = 128;     // v14 fallback: B/16

// ---- workspace layout (bytes); ws >= 90 MiB proven (R11-R14) ----
static constexpr size_t WFH_OFF  = 0;                 // Whh frags: 10 x 512 KiB
static constexpr size_t WFX_OFF  = 5u << 20;          // Wih frags: 10 x 512 KiB
static constexpr size_t HBUF_OFF = 10u << 20;         // h double buffer: 2 MiB
static constexpr size_t CTR_OFF  = 12u << 20;         // team counters: 4 KiB
static constexpr size_t SEQ2_OFF = 26u << 20;         // seq: 64 MiB
static constexpr int    WFL  = 262144;                // u16 per layer frag slot
static constexpr int    TCH  = 4;                     // v14 fallback

// ---------------- small helpers ----------------
__device__ __forceinline__ u16 f2h(float f) {
  _Float16 h = (_Float16)f;
  return __builtin_bit_cast(u16, h);
}
__device__ __forceinline__ float h2f(u16 b) {
  return (float)__builtin_bit_cast(_Float16, b);
}
__device__ __forceinline__ float rcp_(float x) { return __builtin_amdgcn_rcpf(x); }
__device__ __forceinline__ float fsig(float x) { return rcp_(1.f + __expf(-x)); }
__device__ __forceinline__ float ftanh(float x) {
  float e = __expf(-2.f * fabsf(x));
  float t = (1.f - e) * rcp_(1.f + e);
  return copysignf(t, x);
}
__device__ __forceinline__ void gld16(const u16* g, u16* l) {
  __builtin_amdgcn_global_load_lds(
      (const __attribute__((address_space(1))) void*)g,
      (__attribute__((address_space(3))) void*)l,
      16, 0, 0);
}

// =====================================================================
// =================== v15 coop path (persistent W) ====================
// =====================================================================
// Packing for the team decomposition. frag(l, which, cb, gcf, kc):
// element (lane,i) = W[row][k], row = q*256 + cb*32 + (gcf&1)*16 + (lane&15)
// (q = gcf>>1), k = kc*32 + (lane>>4)*8 + i.
// dst = base + l*WFL + ((cb*8 + gcf)*8 + kc)*512 + lane*8
// -> per (l,cb) slab (64 KiB) is contiguous for one-shot DMA into LDS.
__global__ void pack_weights_v15(const float* __restrict__ Wih0,
                                 const float* __restrict__ Wih,
                                 const float* __restrict__ Whh,
                                 u16* __restrict__ wfh,
                                 u16* __restrict__ wfx) {
  int gid = blockIdx.x * 256 + threadIdx.x;
  int l   = gid >> 16;
  if (l >= NL_) return;
  int rem   = gid & 65535;
  int which = rem >> 15;
  int cb    = (rem >> 12) & 7;
  int gcf   = (rem >> 9) & 7;
  int kc    = (rem >> 6) & 7;
  int lane  = rem & 63;
  if (which == 1 && l == 0 && kc >= 2) return;   // layer0 Wih: K=64 -> 2 kc

  int q   = gcf >> 1;
  int row = q * 256 + cb * 32 + (gcf & 1) * 16 + (lane & 15);
  int k0  = kc * 32 + (lane >> 4) * 8;

  float v[8];
#pragma unroll
  for (int i = 0; i < 8; ++i) {
    int k = k0 + i;
    float x;
    if (which == 0)  x = Whh[(size_t)(l * 1024 + row) * 256 + k];
    else if (l == 0) x = Wih0[row * 64 + k];
    else             x = Wih[(size_t)((l - 1) * 1024 + row) * 256 + k];
    v[i] = x;
  }
  u32 pk[4];
#pragma unroll
  for (int i = 0; i < 4; ++i)
    pk[i] = (u32)f2h(v[2 * i]) | ((u32)f2h(v[2 * i + 1]) << 16);
  uint4 val; val.x = pk[0]; val.y = pk[1]; val.z = pk[2]; val.w = pk[3];
  u16* base = (which == 0) ? wfh : wfx;
  u16* dst = base + (size_t)l * WFL
                  + ((size_t)(cb * 8 + gcf) * 8 + kc) * 512 + (size_t)lane * 8;
  *(uint4*)dst = val;
}

// 256 blocks = 32 batch-groups (bg, 64 rows) x 8 col-blocks (cb, 32 h-cols x
// 4 gates). W slice (128 KiB) LDS-RESIDENT per layer -- no per-step W stream.
// Per step: A (x_t, h_{t-1}) in registers from global (single-use loads),
// 32 MFMA vs resident W, gate exchange via LDS (fp16), h -> hbuf[t&1] + seq,
// team sync via device-scope atomic counter (8 blocks; teams independent).
// All 10 layers in one kernel. Requires co-residency: cooperative launch.
__global__ __launch_bounds__(1024, 4) void lstm_coop(
    const float* __restrict__ X,
    u16* __restrict__ seq,
    const u16* __restrict__ wfh,
    const u16* __restrict__ wfx,
    u16* __restrict__ hbuf,          // [2][2048][256] fp16
    u32* __restrict__ ctr,           // [32] team counters (64B spaced)
    const float* __restrict__ b) {
  __shared__ __align__(16) u16 Wl[65536];   // [0,32768): Whh, [32768,65536): Wih
  __shared__ __align__(4)  u16 eg[64][136]; // gate exchange (padded)

  const int tid  = threadIdx.x;
  const int wid  = tid >> 6;
  const int lane = tid & 63;
  const int bg   = blockIdx.x >> 3;
  const int cb   = blockIdx.x & 7;
  const int rf   = wid & 3;          // row-frag (16 rows)
  const int gp   = wid >> 2;         // gate q; handles gcf = 2gp, 2gp+1
  const int arow = lane & 15;
  const int ahi  = lane >> 4;
  u32* myctr = ctr + bg * 16;

  const int nrow = tid >> 4;         // nonlin: row 0..63
  const int nj   = (tid & 15) * 2;   // nonlin: col pair

  v8hf ax[8];
  // prefetch x for (l=0, t=0) from f32 X
  {
    const float* xb = X + ((size_t)(bg * 64 + rf * 16 + arow) * T_ + 0) * D_ + ahi * 8;
#pragma unroll
    for (int kcx = 0; kcx < 2; ++kcx) {
      float4 u = *(const float4*)(xb + kcx * 32);
      float4 w = *(const float4*)(xb + kcx * 32 + 4);
      v8hf a;
      a[0] = (_Float16)u.x; a[1] = (_Float16)u.y;
      a[2] = (_Float16)u.z; a[3] = (_Float16)u.w;
      a[4] = (_Float16)w.x; a[5] = (_Float16)w.y;
      a[6] = (_Float16)w.z; a[7] = (_Float16)w.w;
      ax[kcx] = a;
    }
  }

  for (int l = 0; l < NL_; ++l) {
    // ---- load W slice into LDS (once per layer) ----
    __syncthreads();   // all prior Wl reads done
    {
      const u16* sh = wfh + (size_t)l * WFL + (size_t)cb * 32768;
      const u16* sx = wfx + (size_t)l * WFL + (size_t)cb * 32768;
#pragma unroll
      for (int r = 0; r < 8; ++r)
        gld16(sh + wid * 4096 + r * 512 + (size_t)lane * 8, &Wl[wid * 4096 + r * 512]);
#pragma unroll
      for (int r = 0; r < 8; ++r)
        gld16(sx + wid * 4096 + r * 512 + (size_t)lane * 8, &Wl[32768 + wid * 4096 + r * 512]);
      asm volatile("s_waitcnt vmcnt(0)" ::: "memory");
    }
    __syncthreads();

    const int KCX = (l == 0) ? 2 : 8;
    const float bv0 = b[l * 1024 + gp * 256 + cb * 32 + arow];
    const float bv1 = b[l * 1024 + gp * 256 + cb * 32 + 16 + arow];
    float c0 = 0.f, c1 = 0.f;

    for (int t = 0; t < T_; ++t) {
      const int gs = l * T_ + t;

      // ---- A_h loads (t>0) ----
      v8hf ah[8];
      if (t > 0) {
        const u16* hb = hbuf + (size_t)((t - 1) & 1) * 524288
                             + (size_t)(bg * 64 + rf * 16 + arow) * 256 + ahi * 8;
#pragma unroll
        for (int kh = 0; kh < 8; ++kh)
          ah[kh] = *(const v8hf*)(const void*)(hb + kh * 32);
      }

      f32x4 a0 = {bv0, bv0, bv0, bv0};
      f32x4 a1 = {bv1, bv1, bv1, bv1};

      // ---- x part (A prefetched last iter; W resident) ----
#pragma unroll 2
      for (int kcx = 0; kcx < KCX; ++kcx) {
        v8hf w0 = *(const v8hf*)(const void*)&Wl[32768 + ((2 * gp) * 8 + kcx) * 512 + lane * 8];
        v8hf w1 = *(const v8hf*)(const void*)&Wl[32768 + ((2 * gp + 1) * 8 + kcx) * 512 + lane * 8];
        a0 = __builtin_amdgcn_mfma_f32_16x16x32_f16(ax[kcx], w0, a0, 0, 0, 0);
        a1 = __builtin_amdgcn_mfma_f32_16x16x32_f16(ax[kcx], w1, a1, 0, 0, 0);
      }
      // ---- h part (skip at t=0: h=0 contributes exactly 0) ----
      if (t > 0) {
#pragma unroll
        for (int kh = 0; kh < 8; ++kh) {
          v8hf w0 = *(const v8hf*)(const void*)&Wl[((2 * gp) * 8 + kh) * 512 + lane * 8];
          v8hf w1 = *(const v8hf*)(const void*)&Wl[((2 * gp + 1) * 8 + kh) * 512 + lane * 8];
          a0 = __builtin_amdgcn_mfma_f32_16x16x32_f16(ah[kh], w0, a0, 0, 0, 0);
          a1 = __builtin_amdgcn_mfma_f32_16x16x32_f16(ah[kh], w1, a1, 0, 0, 0);
        }
      }

      // ---- prefetch x for next (layer, step); ordered before sync(t) so the
      //      in-place seq[t+1] overwrite (which happens after sync) is safe ----
      if (!(l == NL_ - 1 && t == T_ - 1)) {
        const int lp = (t < T_ - 1) ? l : l + 1;
        const int tp = (t < T_ - 1) ? t + 1 : 0;
        if (lp == 0) {
          const float* xb = X + ((size_t)(bg * 64 + rf * 16 + arow) * T_ + tp) * D_ + ahi * 8;
#pragma unroll
          for (int kcx = 0; kcx < 2; ++kcx) {
            float4 u = *(const float4*)(xb + kcx * 32);
            float4 w = *(const float4*)(xb + kcx * 32 + 4);
            v8hf a;
            a[0] = (_Float16)u.x; a[1] = (_Float16)u.y;
            a[2] = (_Float16)u.z; a[3] = (_Float16)u.w;
            a[4] = (_Float16)w.x; a[5] = (_Float16)w.y;
            a[6] = (_Float16)w.z; a[7] = (_Float16)w.w;
            ax[kcx] = a;
          }
        } else {
          const int nb = bg * 4 + rf;
          const u16* sb = seq + (((size_t)nb * T_ + tp) * 16 + arow) * 256 + ahi * 8;
#pragma unroll
          for (int k = 0; k < 8; ++k)
            ax[k] = *(const v8hf*)(const void*)(sb + k * 32);
        }
      }

      // ---- gate exchange: D col=lane&15, row=(lane>>4)*4+r [m89] ----
#pragma unroll
      for (int r = 0; r < 4; ++r) {
        eg[rf * 16 + ahi * 4 + r][gp * 32 + arow]      = f2h(a0[r]);
        eg[rf * 16 + ahi * 4 + r][gp * 32 + 16 + arow] = f2h(a1[r]);
      }
      __syncthreads();

      // ---- nonlinearity: thread owns (nrow, cols nj, nj+1) ----
      {
        u32 pi = *(const u32*)&eg[nrow][0 * 32 + nj];
        u32 pf = *(const u32*)&eg[nrow][1 * 32 + nj];
        u32 pg = *(const u32*)&eg[nrow][2 * 32 + nj];
        u32 po = *(const u32*)&eg[nrow][3 * 32 + nj];
        float i0 = h2f((u16)pi), f0 = h2f((u16)pf), g0 = h2f((u16)pg), o0 = h2f((u16)po);
        float i1 = h2f((u16)(pi >> 16)), f1 = h2f((u16)(pf >> 16));
        float g1 = h2f((u16)(pg >> 16)), o1 = h2f((u16)(po >> 16));
        c0 = fsig(f0) * c0 + fsig(i0) * ftanh(g0);
        c1 = fsig(f1) * c1 + fsig(i1) * ftanh(g1);
        float h0 = fsig(o0) * ftanh(c0);
        float h1 = fsig(o1) * ftanh(c1);
        u32 hw = (u32)f2h(h0) | ((u32)f2h(h1) << 16);
        *(u32*)(hbuf + (size_t)(t & 1) * 524288
                     + (size_t)(bg * 64 + nrow) * 256 + cb * 32 + nj) = hw;
        const int nb2 = bg * 4 + (nrow >> 4);
        *(u32*)(seq + (((size_t)nb2 * T_ + t) * 16 + (nrow & 15)) * 256 + cb * 32 + nj) = hw;
      }

      // ---- team sync (release: fence-all + barrier + one atomic) ----
      __threadfence();
      __syncthreads();
      if (tid == 0) {
        atomicAdd(myctr, 1u);
        const u32 tgt = 8u * (u32)(gs + 1);
        while (atomicAdd(myctr, 0u) < tgt) __builtin_amdgcn_s_sleep(2);
      }
      __syncthreads();
      __threadfence();   // acquire side before next step's hbuf/seq reads
    }
  }
}

// =====================================================================
// ===================  v14 fallback (proven 11 ms)  ===================
// =====================================================================
__global__ void pack_weights_v14(const float* __restrict__ Wih0,
                                 const float* __restrict__ Wih,
                                 const float* __restrict__ Whh,
                                 u16* __restrict__ wfh,
                                 u16* __restrict__ wfx) {
  int gid = blockIdx.x * 256 + threadIdx.x;
  int lw  = gid >> 15;
  if (lw >= NL_ * 2) return;
  int l = lw >> 1, which = lw & 1;
  int rem  = gid & 32767;
  int kc   = rem >> 12;
  int cg   = (rem >> 8) & 15;
  int g    = (rem >> 6) & 3;
  int lane = rem & 63;
  if (which == 1 && l == 0 && kc >= 2) return;

  int row = g * 256 + cg * 16 + (lane & 15);
  int k0  = kc * 32 + (lane >> 4) * 8;

  float v[8];
#pragma unroll
  for (int i = 0; i < 8; ++i) {
    int k = k0 + i;
    float x;
    if (which == 0)      x = Whh[(size_t)(l * 1024 + row) * 256 + k];
    else if (l == 0)     x = Wih0[row * 64 + k];
    else                 x = Wih[(size_t)((l - 1) * 1024 + row) * 256 + k];
    v[i] = x;
  }
  u32 pk[4];
#pragma unroll
  for (int i = 0; i < 4; ++i)
    pk[i] = (u32)f2h(v[2 * i]) | ((u32)f2h(v[2 * i + 1]) << 16);
  uint4 val; val.x = pk[0]; val.y = pk[1]; val.z = pk[2]; val.w = pk[3];
  u16* base = (which == 0) ? wfh : wfx;
  u16* dst = base + (size_t)l * WFL
                  + ((size_t)(kc * 16 + cg) * 4 + g) * 512 + (size_t)lane * 8;
  *(uint4*)dst = val;
}

template <bool L0>
__global__ __launch_bounds__(1024, 4) void lstm_layer_v14(
    const float* __restrict__ X,
    u16* __restrict__ seq,
    const u16* __restrict__ wfx_l,
    const u16* __restrict__ wfh_l,
    const float* __restrict__ bias) {
  __shared__ __align__(16) u16 Wring[65536];
  __shared__ __align__(16) u16 Ah[16 * 256];

  const int tid  = threadIdx.x;
  const int wid  = tid >> 6;
  const int lane = tid & 63;
  const int bid  = blockIdx.x;
  const int arow = lane & 15;
  const int ahi  = lane >> 4;
  const int j    = wid * 16 + arow;

  *(uint2*)((char*)Ah + tid * 8) = make_uint2(0, 0);

  float c[4] = {0.f, 0.f, 0.f, 0.f};
  float bv[4];
#pragma unroll
  for (int g = 0; g < 4; ++g) bv[g] = bias[g * 256 + j];

  u16* slot0 = Wring + wid * 2048;
  u16* slot1 = Wring + 32768 + wid * 2048;
  const size_t laneoff = (size_t)lane * 8;

  __syncthreads();

  for (int tc = 0; tc < T_ / TCH; ++tc) {
    f32x4 acc0[TCH][4];
#pragma unroll
    for (int rf = 0; rf < TCH; ++rf)
#pragma unroll
      for (int g = 0; g < 4; ++g) {
        acc0[rf][g][0] = bv[g]; acc0[rf][g][1] = bv[g];
        acc0[rf][g][2] = bv[g]; acc0[rf][g][3] = bv[g];
      }

    if constexpr (L0) {
#pragma unroll
      for (int g = 0; g < 4; ++g) {
        gld16(wfx_l + ((size_t)(0 * 16 + wid) * 4 + g) * 512 + laneoff, slot0 + g * 512);
        gld16(wfx_l + ((size_t)(1 * 16 + wid) * 4 + g) * 512 + laneoff, slot1 + g * 512);
      }
      asm volatile("s_waitcnt vmcnt(0)" ::: "memory");
      __builtin_amdgcn_sched_barrier(0);
      const float* xb = X + ((size_t)(bid * 16 + arow) * T_ + tc * TCH) * D_ + ahi * 8;
#pragma unroll
      for (int kc = 0; kc < 2; ++kc) {
        const u16* wl = (kc ? slot1 : slot0) + lane * 8;
        v8hf af[TCH];
#pragma unroll
        for (int rf = 0; rf < TCH; ++rf) {
          float4 u = *(const float4*)(xb + rf * D_ + kc * 32);
          float4 v2 = *(const float4*)(xb + rf * D_ + kc * 32 + 4);
          v8hf a;
          a[0] = (_Float16)u.x;  a[1] = (_Float16)u.y;
          a[2] = (_Float16)u.z;  a[3] = (_Float16)u.w;
          a[4] = (_Float16)v2.x; a[5] = (_Float16)v2.y;
          a[6] = (_Float16)v2.z; a[7] = (_Float16)v2.w;
          af[rf] = a;
        }
#pragma unroll
        for (int g = 0; g < 4; ++g) {
          v8hf w = *(const v8hf*)(const void*)(wl + g * 512);
#pragma unroll
          for (int rf = 0; rf < TCH; ++rf)
            acc0[rf][g] = __builtin_amdgcn_mfma_f32_16x16x32_f16(af[rf], w, acc0[rf][g], 0, 0, 0);
        }
      }
    } else {
      const u16* abase = seq + ((size_t)(bid * T_ + tc * TCH) * 16 + arow) * 256 + ahi * 8;
      v8hf aA[TCH], aB[TCH];
#pragma unroll
      for (int g = 0; g < 4; ++g)
        gld16(wfx_l + ((size_t)(0 * 16 + wid) * 4 + g) * 512 + laneoff, slot0 + g * 512);
#pragma unroll
      for (int rf = 0; rf < TCH; ++rf)
        aA[rf] = *(const v8hf*)(const void*)(abase + rf * 4096);

#pragma unroll
      for (int kc = 0; kc < 8; ++kc) {
        if (kc < 7) {
          u16* nd = ((kc + 1) & 1) ? slot1 : slot0;
#pragma unroll
          for (int g = 0; g < 4; ++g)
            gld16(wfx_l + ((size_t)((kc + 1) * 16 + wid) * 4 + g) * 512 + laneoff, nd + g * 512);
          if ((kc & 1) == 0) {
#pragma unroll
            for (int rf = 0; rf < TCH; ++rf)
              aB[rf] = *(const v8hf*)(const void*)(abase + rf * 4096 + (kc + 1) * 32);
          } else {
#pragma unroll
            for (int rf = 0; rf < TCH; ++rf)
              aA[rf] = *(const v8hf*)(const void*)(abase + rf * 4096 + (kc + 1) * 32);
          }
          asm volatile("s_waitcnt vmcnt(8)" ::: "memory");
        } else {
          asm volatile("s_waitcnt vmcnt(0)" ::: "memory");
        }
        __builtin_amdgcn_sched_barrier(0);
        const u16* wl = ((kc & 1) ? slot1 : slot0) + lane * 8;
#pragma unroll
        for (int g = 0; g < 4; ++g) {
          v8hf w = *(const v8hf*)(const void*)(wl + g * 512);
#pragma unroll
          for (int rf = 0; rf < TCH; ++rf)
            acc0[rf][g] = __builtin_amdgcn_mfma_f32_16x16x32_f16(
                ((kc & 1) ? aB[rf] : aA[rf]), w, acc0[rf][g], 0, 0, 0);
        }
      }
    }

#pragma unroll
    for (int g = 0; g < 4; ++g)
      gld16(wfh_l + ((size_t)(0 * 16 + wid) * 4 + g) * 512 + laneoff, slot0 + g * 512);
#pragma unroll
    for (int g = 0; g < 4; ++g)
      gld16(wfh_l + ((size_t)(1 * 16 + wid) * 4 + g) * 512 + laneoff, slot1 + g * 512);

    uint2 xr[TCH][4];
#pragma unroll
    for (int rf = 0; rf < TCH; ++rf)
#pragma unroll
      for (int g = 0; g < 4; ++g) {
        xr[rf][g].x = (u32)f2h(acc0[rf][g][0]) | ((u32)f2h(acc0[rf][g][1]) << 16);
        xr[rf][g].y = (u32)f2h(acc0[rf][g][2]) | ((u32)f2h(acc0[rf][g][3]) << 16);
      }

#pragma unroll
    for (int tl = 0; tl < TCH; ++tl) {
      const int t = tc * TCH + tl;
      f32x4 acc[4];
#pragma unroll
      for (int g = 0; g < 4; ++g) {
        acc[g][0] = h2f((u16)(xr[tl][g].x & 0xffff));
        acc[g][1] = h2f((u16)(xr[tl][g].x >> 16));
        acc[g][2] = h2f((u16)(xr[tl][g].y & 0xffff));
        acc[g][3] = h2f((u16)(xr[tl][g].y >> 16));
      }

#pragma unroll
      for (int kc = 0; kc < 8; ++kc) {
        if (kc < 7) asm volatile("s_waitcnt vmcnt(4)" ::: "memory");
        else        asm volatile("s_waitcnt vmcnt(0)" ::: "memory");
        __builtin_amdgcn_sched_barrier(0);

        v8hf a = *(const v8hf*)((const char*)Ah + arow * 512 +
                                ((kc * 64 + ahi * 16) ^ ((arow & 7) << 4)));
        const u16* wl = ((kc & 1) ? slot1 : slot0) + lane * 8;
#pragma unroll
        for (int g = 0; g < 4; ++g) {
          v8hf w = *(const v8hf*)(const void*)(wl + g * 512);
          acc[g] = __builtin_amdgcn_mfma_f32_16x16x32_f16(a, w, acc[g], 0, 0, 0);
        }
        if (kc < 6) {
          u16* nd = (kc & 1) ? slot1 : slot0;
#pragma unroll
          for (int g = 0; g < 4; ++g)
            gld16(wfh_l + ((size_t)((kc + 2) * 16 + wid) * 4 + g) * 512 + laneoff,
                  nd + g * 512);
        }
      }
      __syncthreads();

      if (tl + 1 < TCH) {
#pragma unroll
        for (int g = 0; g < 4; ++g)
          gld16(wfh_l + ((size_t)(0 * 16 + wid) * 4 + g) * 512 + laneoff, slot0 + g * 512);
#pragma unroll
        for (int g = 0; g < 4; ++g)
          gld16(wfh_l + ((size_t)(1 * 16 + wid) * 4 + g) * 512 + laneoff, slot1 + g * 512);
      }

      u16* sbase = seq + ((((size_t)bid * T_ + t) * 16) << 8) + j;
#pragma unroll
      for (int q = 0; q < 4; ++q) {
        int r = ahi * 4 + q;
        float cn = fsig(acc[1][q]) * c[q] + fsig(acc[0][q]) * ftanh(acc[2][q]);
        c[q] = cn;
        float h = fsig(acc[3][q]) * ftanh(cn);
        u16 hb = f2h(h);
        sbase[(size_t)r << 8] = hb;
        *(u16*)((char*)Ah + r * 512 + ((j * 2) ^ ((r & 7) << 4))) = hb;
      }
      __syncthreads();
    }
  }
}

// ---------------- tail (encoder / sample / decoder) ----------------
template <int N, int K, bool RELU>
__device__ __forceinline__ void dense(const float (*__restrict__ in)[512],
                                      float (*__restrict__ out)[512],
                                      const float* __restrict__ W,
                                      const float* __restrict__ bg, int tid) {
  for (int e = tid; e < 16 * N; e += 256) {
    int r = e / N, n = e - r * N;
    const float* wr = W + (size_t)n * K;
    const float* ar = in[r];
    float4 acc = {0.f, 0.f, 0.f, 0.f};
    for (int k = 0; k < K; k += 4) {
      float4 wv = *(const float4*)(wr + k);
      float4 av = *(const float4*)(ar + k);
      acc.x = fmaf(wv.x, av.x, acc.x);
      acc.y = fmaf(wv.y, av.y, acc.y);
      acc.z = fmaf(wv.z, av.z, acc.z);
      acc.w = fmaf(wv.w, av.w, acc.w);
    }
    float s = bg[n] + acc.x + acc.y + acc.z + acc.w;
    out[r][n] = RELU ? fmaxf(s, 0.f) : s;
  }
}

template <int K>
__device__ __forceinline__ float dotK(const float* __restrict__ a, const float* __restrict__ w) {
  float4 acc = {0.f, 0.f, 0.f, 0.f};
#pragma unroll
  for (int k = 0; k < K; k += 4) {
    float4 wv = *(const float4*)(w + k);
    float4 av = *(const float4*)(a + k);
    acc.x = fmaf(wv.x, av.x, acc.x);
    acc.y = fmaf(wv.y, av.y, acc.y);
    acc.z = fmaf(wv.z, av.z, acc.z);
    acc.w = fmaf(wv.w, av.w, acc.w);
  }
  return acc.x + acc.y + acc.z + acc.w;
}

struct TailArgs {
  const u16* seq;
  const float *ef1w, *ef1b, *ef2w, *ef2b;
  const float *mean_w, *mean_b, *logvar_w, *logvar_b;
  const float *scale_w, *scale_b, *shape_w, *shape_b;
  const float *df1w, *df1b, *df2w, *df2b, *outw, *outb, *finw, *finb;
  const float *pi, *eps, *u, *choice;
  float* out;
};

__global__ __launch_bounds__(256) void tail_kernel_v15(TailArgs A) {
  __shared__ float a0[16][512];
  __shared__ float a1[16][512];
  const int tid = threadIdx.x, bid = blockIdx.x;

  for (int e = tid; e < 16 * 256; e += 256) {
    int r = e >> 8, jj = e & 255;
    a0[r][jj] = h2f(A.seq[((((size_t)bid * T_ + (T_ - 1)) * 16 + r) << 8) + jj]);
  }
  __syncthreads();

  dense<128, 256, true>(a0, a1, A.ef1w, A.ef1b, tid); __syncthreads();
  dense<64, 128, true>(a1, a0, A.ef2w, A.ef2b, tid);  __syncthreads();

  const float pi = *A.pi;
  for (int e = tid; e < 16 * 64; e += 256) {
    int r = e >> 6, n = e & 63;
    size_t rg = (size_t)bid * 16 + r;
    float m  = dotK<64>(a0[r], A.mean_w   + n * 64) + A.mean_b[n];
    float lv = dotK<64>(a0[r], A.logvar_w + n * 64) + A.logvar_b[n];
    float sc = __expf(dotK<64>(a0[r], A.scale_w + n * 64) + A.scale_b[n]);
    float sh = dotK<64>(a0[r], A.shape_w + n * 64) + A.shape_b[n];
    A.out[196608 + rg * 64 + n] = m;
    A.out[327680 + rg * 64 + n] = lv;
    A.out[458752 + rg * 64 + n] = sc;
    A.out[589824 + rg * 64 + n] = sh;
    float zg = m + A.eps[rg * 64 + n] * __expf(0.5f * lv);
    float L  = log1pf(-A.u[rg * 64 + n]);
    float zp = sc / sh * (__expf(-sh * L) - 1.f);
    a1[r][n] = (A.choice[rg] < pi) ? zg : zp;
  }
  __syncthreads();

  dense<128, 64, true>(a1, a0, A.df1w, A.df1b, tid);   __syncthreads();
  dense<500, 128, true>(a0, a1, A.df2w, A.df2b, tid);  __syncthreads();
  dense<96, 500, false>(a1, a0, A.outw, A.outb, tid);  __syncthreads();
  dense<96, 96, false>(a0, a1, A.finw, A.finb, tid);   __syncthreads();

  for (int e = tid; e < 16 * FUT_; e += 256) {
    int r = e / FUT_, n = e - r * FUT_;
    A.out[((size_t)bid * 16 + r) * FUT_ + n] = a1[r][n];
  }
}

// ---------------- launch ----------------
extern "C" void kernel_launch(void* const* d_in, const int* in_sizes, int n_in,
                              void* d_out, int out_size, void* d_ws, size_t ws_size,
                              hipStream_t stream) {
  (void)in_sizes; (void)n_in; (void)out_size; (void)ws_size;

  const float* X      = (const float*)d_in[0];
  const float* Wih0   = (const float*)d_in[1];
  const float* Wih    = (const float*)d_in[2];
  const float* Whh    = (const float*)d_in[3];
  const float* b      = (const float*)d_in[4];
  const float* ef1w   = (const float*)d_in[5];
  const float* ef1b   = (const float*)d_in[6];
  const float* ef2w   = (const float*)d_in[7];
  const float* ef2b   = (const float*)d_in[8];
  const float* mean_w = (const float*)d_in[9];
  const float* mean_b = (const float*)d_in[10];
  const float* logvar_w = (const float*)d_in[11];
  const float* logvar_b = (const float*)d_in[12];
  const float* scale_w  = (const float*)d_in[13];
  const float* scale_b  = (const float*)d_in[14];
  const float* shape_w  = (const float*)d_in[15];
  const float* shape_b  = (const float*)d_in[16];
  const float* df1w   = (const float*)d_in[17];
  const float* df1b   = (const float*)d_in[18];
  const float* df2w   = (const float*)d_in[19];
  const float* df2b   = (const float*)d_in[20];
  const float* outw   = (const float*)d_in[21];
  const float* outb   = (const float*)d_in[22];
  const float* finw   = (const float*)d_in[23];
  const float* finb   = (const float*)d_in[24];
  const float* pi_g   = (const float*)d_in[25];
  const float* eps    = (const float*)d_in[26];
  const float* u      = (const float*)d_in[27];
  const float* choice = (const float*)d_in[28];

  float* out = (float*)d_out;
  u16* wfh  = (u16*)((char*)d_ws + WFH_OFF);
  u16* wfx  = (u16*)((char*)d_ws + WFX_OFF);
  u16* hbuf = (u16*)((char*)d_ws + HBUF_OFF);
  u32* ctr  = (u32*)((char*)d_ws + CTR_OFF);
  u16* seq  = (u16*)((char*)d_ws + SEQ2_OFF);

  pack_weights_v15<<<2560, 256, 0, stream>>>(Wih0, Wih, Whh, wfh, wfx);
  hipMemsetAsync((void*)ctr, 0, 4096, stream);

  const float* Xa = X; u16* seqa = seq; const u16* wfha = wfh; const u16* wfxa = wfx;
  u16* hbufa = hbuf; u32* ctra = ctr; const float* ba = b;
  void* params[] = {&Xa, &seqa, &wfha, &wfxa, &hbufa, &ctra, &ba};
  hipError_t e = hipLaunchCooperativeKernel((void*)lstm_coop, dim3(256), dim3(1024),
                                            params, 0, stream);
  if (e != hipSuccess) {
    // fallback: proven v14 path (repack in v14 layout, same regions)
    pack_weights_v14<<<2560, 256, 0, stream>>>(Wih0, Wih, Whh, wfh, wfx);
    lstm_layer_v14<true><<<NBLK, 1024, 0, stream>>>(X, seq, wfx, wfh, b);
    for (int l = 1; l < NL_; ++l)
      lstm_layer_v14<false><<<NBLK, 1024, 0, stream>>>(nullptr, seq,
          wfx + (size_t)l * WFL, wfh + (size_t)l * WFL, b + l * 1024);
  }

  TailArgs A;
  A.seq = seq;
  A.ef1w = ef1w; A.ef1b = ef1b; A.ef2w = ef2w; A.ef2b = ef2b;
  A.mean_w = mean_w; A.mean_b = mean_b; A.logvar_w = logvar_w; A.logvar_b = logvar_b;
  A.scale_w = scale_w; A.scale_b = scale_b; A.shape_w = shape_w; A.shape_b = shape_b;
  A.df1w = df1w; A.df1b = df1b; A.df2w = df2w; A.df2b = df2b;
  A.outw = outw; A.outb = outb; A.finw = finw; A.finb = finb;
  A.pi = pi_g; A.eps = eps; A.u = u; A.choice = choice;
  A.out = out;
  tail_kernel_v15<<<NBLK, 256, 0, stream>>>(A);
}

// Round 16
// 77076.422 us; speedup vs baseline: 2.0634x; 2.0634x over previous
//
#include <hip/hip_runtime.h>

typedef unsigned short u16;
typedef unsigned int   u32;
typedef unsigned long long u64;
typedef _Float16 v8hf __attribute__((ext_vector_type(8)));
typedef float  f32x4 __attribute__((ext_vector_type(4)));

// ---------------- problem constants ----------------
static constexpr int B_   = 2048;
static constexpr int T_   = 64;
static constexpr int D_   = 64;
static constexpr int H_   = 256;
static constexpr int NL_  = 10;
static constexpr int FUT_ = 96;
static constexpr int NBLK = 128;     // v14 fallback: B/16

// ---- workspace layout (bytes); proven fits ----
static constexpr size_t WFH_OFF  = 0;                 // Whh frags: 10 x 512 KiB
static constexpr size_t WFX_OFF  = 5u << 20;          // Wih frags: 10 x 512 KiB
static constexpr size_t CTR_OFF  = 12u << 20;         // team counters: 4 KiB
static constexpr size_t SEQ2_OFF = 26u << 20;         // seq: 64 MiB
static constexpr int    WFL  = 262144;                // u16 per layer frag slot
static constexpr int    TCH  = 4;                     // v14 fallback

// ---------------- small helpers ----------------
__device__ __forceinline__ u16 f2h(float f) {
  _Float16 h = (_Float16)f;
  return __builtin_bit_cast(u16, h);
}
__device__ __forceinline__ float h2f(u16 b) {
  return (float)__builtin_bit_cast(_Float16, b);
}
__device__ __forceinline__ float rcp_(float x) { return __builtin_amdgcn_rcpf(x); }
__device__ __forceinline__ float fsig(float x) { return rcp_(1.f + __expf(-x)); }
__device__ __forceinline__ float ftanh(float x) {
  float e = __expf(-2.f * fabsf(x));
  float t = (1.f - e) * rcp_(1.f + e);
  return copysignf(t, x);
}
__device__ __forceinline__ void gld16(const u16* g, u16* l) {
  __builtin_amdgcn_global_load_lds(
      (const __attribute__((address_space(1))) void*)g,
      (__attribute__((address_space(3))) void*)l,
      16, 0, 0);
}
// device-scope (agent) relaxed 16B load: bypasses non-coherent local L2,
// served at the device coherence point; also remat-proof (atomic).
__device__ __forceinline__ v8hf ald16(const u16* p) {
  const u64* q = (const u64*)p;
  u64 a = __hip_atomic_load(q,     __ATOMIC_RELAXED, __HIP_MEMORY_SCOPE_AGENT);
  u64 b = __hip_atomic_load(q + 1, __ATOMIC_RELAXED, __HIP_MEMORY_SCOPE_AGENT);
  struct P { u64 x, y; } pr{a, b};
  return __builtin_bit_cast(v8hf, pr);
}
__device__ __forceinline__ void ast32(u16* p, u32 v) {
  __hip_atomic_store((u32*)p, v, __ATOMIC_RELAXED, __HIP_MEMORY_SCOPE_AGENT);
}

// =====================================================================
// =================== v16 coop path (persistent W) ====================
// =====================================================================
// frag(l, which, cb, gcf, kc): element (lane,i) = W[row][k],
// row = (gcf>>1)*256 + cb*32 + (gcf&1)*16 + (lane&15), k = kc*32 + (lane>>4)*8 + i.
// dst = base + l*WFL + ((cb*8 + gcf)*8 + kc)*512 + lane*8  (64 KiB slab per (l,cb))
__global__ void pack_weights_v16(const float* __restrict__ Wih0,
                                 const float* __restrict__ Wih,
                                 const float* __restrict__ Whh,
                                 u16* __restrict__ wfh,
                                 u16* __restrict__ wfx) {
  int gid = blockIdx.x * 256 + threadIdx.x;
  int l   = gid >> 16;
  if (l >= NL_) return;
  int rem   = gid & 65535;
  int which = rem >> 15;
  int cb    = (rem >> 12) & 7;
  int gcf   = (rem >> 9) & 7;
  int kc    = (rem >> 6) & 7;
  int lane  = rem & 63;
  if (which == 1 && l == 0 && kc >= 2) return;   // layer0 Wih: K=64 -> 2 kc

  int q   = gcf >> 1;
  int row = q * 256 + cb * 32 + (gcf & 1) * 16 + (lane & 15);
  int k0  = kc * 32 + (lane >> 4) * 8;

  float v[8];
#pragma unroll
  for (int i = 0; i < 8; ++i) {
    int k = k0 + i;
    float x;
    if (which == 0)  x = Whh[(size_t)(l * 1024 + row) * 256 + k];
    else if (l == 0) x = Wih0[row * 64 + k];
    else             x = Wih[(size_t)((l - 1) * 1024 + row) * 256 + k];
    v[i] = x;
  }
  u32 pk[4];
#pragma unroll
  for (int i = 0; i < 4; ++i)
    pk[i] = (u32)f2h(v[2 * i]) | ((u32)f2h(v[2 * i + 1]) << 16);
  uint4 val; val.x = pk[0]; val.y = pk[1]; val.z = pk[2]; val.w = pk[3];
  u16* base = (which == 0) ? wfh : wfx;
  u16* dst = base + (size_t)l * WFL
                  + ((size_t)(cb * 8 + gcf) * 8 + kc) * 512 + (size_t)lane * 8;
  *(uint4*)dst = val;
}

// 256 blocks = 32 teams (bg, 64 batch rows) x 8 col-blocks (cb, 32 h-cols x 4
// gates). W slice (128 KiB) LDS-RESIDENT per layer. Cross-block h exchange
// through seq via device-scope relaxed atomics (NO fences -> no L2 flushes).
// Team sync: vmcnt(0) drain (release: h stores + prefetch loads performed),
// one relaxed atomic add, relaxed atomic-load spin (tid 0 only).
__global__ __launch_bounds__(1024, 4) void lstm_coop_v16(
    const float* __restrict__ X,
    u16* __restrict__ seq,           // [128][T][16][256] fp16
    const u16* __restrict__ wfh,
    const u16* __restrict__ wfx,
    u32* __restrict__ ctr,           // [32] team counters (64B spaced)
    const float* __restrict__ b) {
  __shared__ __align__(16) u16 Wl[65536];   // [0,32768): Whh, [32768,65536): Wih
  __shared__ __align__(4)  u16 eg[64][136]; // gate exchange (padded)

  const int tid  = threadIdx.x;
  const int wid  = tid >> 6;
  const int lane = tid & 63;
  const int bg   = blockIdx.x >> 3;
  const int cb   = blockIdx.x & 7;
  const int rf   = wid & 3;          // row-frag (16 rows)
  const int gp   = wid >> 2;         // gate q; handles gcf = 2gp, 2gp+1
  const int arow = lane & 15;
  const int ahi  = lane >> 4;
  u32* myctr = ctr + bg * 16;

  const int nrow = tid >> 4;         // nonlin: row 0..63
  const int nj   = (tid & 15) * 2;   // nonlin: col pair

  v8hf ax[8];
  // prefetch x for (l=0, t=0) from f32 X (input: plain loads fine)
  {
    const float* xb = X + ((size_t)(bg * 64 + rf * 16 + arow) * T_ + 0) * D_ + ahi * 8;
#pragma unroll
    for (int kcx = 0; kcx < 2; ++kcx) {
      float4 u = *(const float4*)(xb + kcx * 32);
      float4 w = *(const float4*)(xb + kcx * 32 + 4);
      v8hf a;
      a[0] = (_Float16)u.x; a[1] = (_Float16)u.y;
      a[2] = (_Float16)u.z; a[3] = (_Float16)u.w;
      a[4] = (_Float16)w.x; a[5] = (_Float16)w.y;
      a[6] = (_Float16)w.z; a[7] = (_Float16)w.w;
      ax[kcx] = a;
    }
  }

  for (int l = 0; l < NL_; ++l) {
    // ---- load W slice into LDS (once per layer) ----
    __syncthreads();   // all prior Wl reads done
    {
      const u16* sh = wfh + (size_t)l * WFL + (size_t)cb * 32768;
      const u16* sx = wfx + (size_t)l * WFL + (size_t)cb * 32768;
#pragma unroll
      for (int r = 0; r < 8; ++r)
        gld16(sh + wid * 4096 + r * 512 + (size_t)lane * 8, &Wl[wid * 4096 + r * 512]);
#pragma unroll
      for (int r = 0; r < 8; ++r)
        gld16(sx + wid * 4096 + r * 512 + (size_t)lane * 8, &Wl[32768 + wid * 4096 + r * 512]);
      asm volatile("s_waitcnt vmcnt(0)" ::: "memory");
    }
    __syncthreads();

    const int KCX = (l == 0) ? 2 : 8;
    const float bv0 = b[l * 1024 + gp * 256 + cb * 32 + arow];
    const float bv1 = b[l * 1024 + gp * 256 + cb * 32 + 16 + arow];
    float c0 = 0.f, c1 = 0.f;

    for (int t = 0; t < T_; ++t) {
      const int gs = l * T_ + t;

      // ---- A_h loads (t>0): h(t-1) of CURRENT layer from seq[t-1],
      //      device-scope (written by team members last step) ----
      v8hf ah[8];
      if (t > 0) {
        const u16* hb = seq + (((size_t)(bg * 4 + rf) * T_ + (t - 1)) * 16 + arow) * 256 + ahi * 8;
#pragma unroll
        for (int kh = 0; kh < 8; ++kh)
          ah[kh] = ald16(hb + kh * 32);
      }

      f32x4 a0 = {bv0, bv0, bv0, bv0};
      f32x4 a1 = {bv1, bv1, bv1, bv1};

      // ---- x part (A prefetched last iter; W resident) ----
#pragma unroll 2
      for (int kcx = 0; kcx < KCX; ++kcx) {
        v8hf w0 = *(const v8hf*)(const void*)&Wl[32768 + ((2 * gp) * 8 + kcx) * 512 + lane * 8];
        v8hf w1 = *(const v8hf*)(const void*)&Wl[32768 + ((2 * gp + 1) * 8 + kcx) * 512 + lane * 8];
        a0 = __builtin_amdgcn_mfma_f32_16x16x32_f16(ax[kcx], w0, a0, 0, 0, 0);
        a1 = __builtin_amdgcn_mfma_f32_16x16x32_f16(ax[kcx], w1, a1, 0, 0, 0);
      }
      // ---- h part (skip at t=0: h=0 contributes exactly 0) ----
      if (t > 0) {
#pragma unroll
        for (int kh = 0; kh < 8; ++kh) {
          v8hf w0 = *(const v8hf*)(const void*)&Wl[((2 * gp) * 8 + kh) * 512 + lane * 8];
          v8hf w1 = *(const v8hf*)(const void*)&Wl[((2 * gp + 1) * 8 + kh) * 512 + lane * 8];
          a0 = __builtin_amdgcn_mfma_f32_16x16x32_f16(ah[kh], w0, a0, 0, 0, 0);
          a1 = __builtin_amdgcn_mfma_f32_16x16x32_f16(ah[kh], w1, a1, 0, 0, 0);
        }
      }

      // ---- prefetch x for next (layer, step): reads seq[t+1] (prev layer's
      //      data) / seq[0] at layer boundary. Device-scope atomic loads;
      //      drained by the vmcnt(0) before sync -> ordered before any
      //      post-sync overwrite of that slot. ----
      if (!(l == NL_ - 1 && t == T_ - 1)) {
        const int lp = (t < T_ - 1) ? l : l + 1;
        const int tp = (t < T_ - 1) ? t + 1 : 0;
        if (lp == 0) {
          const float* xb = X + ((size_t)(bg * 64 + rf * 16 + arow) * T_ + tp) * D_ + ahi * 8;
#pragma unroll
          for (int kcx = 0; kcx < 2; ++kcx) {
            float4 u = *(const float4*)(xb + kcx * 32);
            float4 w = *(const float4*)(xb + kcx * 32 + 4);
            v8hf a;
            a[0] = (_Float16)u.x; a[1] = (_Float16)u.y;
            a[2] = (_Float16)u.z; a[3] = (_Float16)u.w;
            a[4] = (_Float16)w.x; a[5] = (_Float16)w.y;
            a[6] = (_Float16)w.z; a[7] = (_Float16)w.w;
            ax[kcx] = a;
          }
        } else {
          const u16* sb = seq + (((size_t)(bg * 4 + rf) * T_ + tp) * 16 + arow) * 256 + ahi * 8;
#pragma unroll
          for (int k = 0; k < 8; ++k)
            ax[k] = ald16(sb + k * 32);
        }
      }

      // ---- gate exchange: D col=lane&15, row=(lane>>4)*4+r [m89] ----
#pragma unroll
      for (int r = 0; r < 4; ++r) {
        eg[rf * 16 + ahi * 4 + r][gp * 32 + arow]      = f2h(a0[r]);
        eg[rf * 16 + ahi * 4 + r][gp * 32 + 16 + arow] = f2h(a1[r]);
      }
      __syncthreads();

      // ---- nonlinearity: thread owns (nrow, cols nj, nj+1) ----
      {
        u32 pi = *(const u32*)&eg[nrow][0 * 32 + nj];
        u32 pf = *(const u32*)&eg[nrow][1 * 32 + nj];
        u32 pg = *(const u32*)&eg[nrow][2 * 32 + nj];
        u32 po = *(const u32*)&eg[nrow][3 * 32 + nj];
        float i0 = h2f((u16)pi), f0 = h2f((u16)pf), g0 = h2f((u16)pg), o0 = h2f((u16)po);
        float i1 = h2f((u16)(pi >> 16)), f1 = h2f((u16)(pf >> 16));
        float g1 = h2f((u16)(pg >> 16)), o1 = h2f((u16)(po >> 16));
        c0 = fsig(f0) * c0 + fsig(i0) * ftanh(g0);
        c1 = fsig(f1) * c1 + fsig(i1) * ftanh(g1);
        float h0 = fsig(o0) * ftanh(c0);
        float h1 = fsig(o1) * ftanh(c1);
        u32 hw = (u32)f2h(h0) | ((u32)f2h(h1) << 16);
        const int nb2 = bg * 4 + (nrow >> 4);
        ast32(seq + (((size_t)nb2 * T_ + t) * 16 + (nrow & 15)) * 256 + cb * 32 + nj, hw);
      }
      __syncthreads();   // eg reads done before next step's eg writes

      // ---- team sync: release = vmcnt(0) (h stores + prefetch loads
      //      performed at coherence point), then one atomic; NO fences ----
      asm volatile("s_waitcnt vmcnt(0)" ::: "memory");
      __syncthreads();
      if (tid == 0) {
        __hip_atomic_fetch_add(myctr, 1u, __ATOMIC_RELAXED, __HIP_MEMORY_SCOPE_AGENT);
        const u32 tgt = 8u * (u32)(gs + 1);
        while (__hip_atomic_load(myctr, __ATOMIC_RELAXED, __HIP_MEMORY_SCOPE_AGENT) < tgt)
          __builtin_amdgcn_s_sleep(1);
      }
      __syncthreads();
    }
  }
}

// =====================================================================
// ===================  v14 fallback (proven 11 ms)  ===================
// =====================================================================
__global__ void pack_weights_v14(const float* __restrict__ Wih0,
                                 const float* __restrict__ Wih,
                                 const float* __restrict__ Whh,
                                 u16* __restrict__ wfh,
                                 u16* __restrict__ wfx) {
  int gid = blockIdx.x * 256 + threadIdx.x;
  int lw  = gid >> 15;
  if (lw >= NL_ * 2) return;
  int l = lw >> 1, which = lw & 1;
  int rem  = gid & 32767;
  int kc   = rem >> 12;
  int cg   = (rem >> 8) & 15;
  int g    = (rem >> 6) & 3;
  int lane = rem & 63;
  if (which == 1 && l == 0 && kc >= 2) return;

  int row = g * 256 + cg * 16 + (lane & 15);
  int k0  = kc * 32 + (lane >> 4) * 8;

  float v[8];
#pragma unroll
  for (int i = 0; i < 8; ++i) {
    int k = k0 + i;
    float x;
    if (which == 0)      x = Whh[(size_t)(l * 1024 + row) * 256 + k];
    else if (l == 0)     x = Wih0[row * 64 + k];
    else                 x = Wih[(size_t)((l - 1) * 1024 + row) * 256 + k];
    v[i] = x;
  }
  u32 pk[4];
#pragma unroll
  for (int i = 0; i < 4; ++i)
    pk[i] = (u32)f2h(v[2 * i]) | ((u32)f2h(v[2 * i + 1]) << 16);
  uint4 val; val.x = pk[0]; val.y = pk[1]; val.z = pk[2]; val.w = pk[3];
  u16* base = (which == 0) ? wfh : wfx;
  u16* dst = base + (size_t)l * WFL
                  + ((size_t)(kc * 16 + cg) * 4 + g) * 512 + (size_t)lane * 8;
  *(uint4*)dst = val;
}

template <bool L0>
__global__ __launch_bounds__(1024, 4) void lstm_layer_v14(
    const float* __restrict__ X,
    u16* __restrict__ seq,
    const u16* __restrict__ wfx_l,
    const u16* __restrict__ wfh_l,
    const float* __restrict__ bias) {
  __shared__ __align__(16) u16 Wring[65536];
  __shared__ __align__(16) u16 Ah[16 * 256];

  const int tid  = threadIdx.x;
  const int wid  = tid >> 6;
  const int lane = tid & 63;
  const int bid  = blockIdx.x;
  const int arow = lane & 15;
  const int ahi  = lane >> 4;
  const int j    = wid * 16 + arow;

  *(uint2*)((char*)Ah + tid * 8) = make_uint2(0, 0);

  float c[4] = {0.f, 0.f, 0.f, 0.f};
  float bv[4];
#pragma unroll
  for (int g = 0; g < 4; ++g) bv[g] = bias[g * 256 + j];

  u16* slot0 = Wring + wid * 2048;
  u16* slot1 = Wring + 32768 + wid * 2048;
  const size_t laneoff = (size_t)lane * 8;

  __syncthreads();

  for (int tc = 0; tc < T_ / TCH; ++tc) {
    f32x4 acc0[TCH][4];
#pragma unroll
    for (int rf = 0; rf < TCH; ++rf)
#pragma unroll
      for (int g = 0; g < 4; ++g) {
        acc0[rf][g][0] = bv[g]; acc0[rf][g][1] = bv[g];
        acc0[rf][g][2] = bv[g]; acc0[rf][g][3] = bv[g];
      }

    if constexpr (L0) {
#pragma unroll
      for (int g = 0; g < 4; ++g) {
        gld16(wfx_l + ((size_t)(0 * 16 + wid) * 4 + g) * 512 + laneoff, slot0 + g * 512);
        gld16(wfx_l + ((size_t)(1 * 16 + wid) * 4 + g) * 512 + laneoff, slot1 + g * 512);
      }
      asm volatile("s_waitcnt vmcnt(0)" ::: "memory");
      __builtin_amdgcn_sched_barrier(0);
      const float* xb = X + ((size_t)(bid * 16 + arow) * T_ + tc * TCH) * D_ + ahi * 8;
#pragma unroll
      for (int kc = 0; kc < 2; ++kc) {
        const u16* wl = (kc ? slot1 : slot0) + lane * 8;
        v8hf af[TCH];
#pragma unroll
        for (int rf = 0; rf < TCH; ++rf) {
          float4 u = *(const float4*)(xb + rf * D_ + kc * 32);
          float4 v2 = *(const float4*)(xb + rf * D_ + kc * 32 + 4);
          v8hf a;
          a[0] = (_Float16)u.x;  a[1] = (_Float16)u.y;
          a[2] = (_Float16)u.z;  a[3] = (_Float16)u.w;
          a[4] = (_Float16)v2.x; a[5] = (_Float16)v2.y;
          a[6] = (_Float16)v2.z; a[7] = (_Float16)v2.w;
          af[rf] = a;
        }
#pragma unroll
        for (int g = 0; g < 4; ++g) {
          v8hf w = *(const v8hf*)(const void*)(wl + g * 512);
#pragma unroll
          for (int rf = 0; rf < TCH; ++rf)
            acc0[rf][g] = __builtin_amdgcn_mfma_f32_16x16x32_f16(af[rf], w, acc0[rf][g], 0, 0, 0);
        }
      }
    } else {
      const u16* abase = seq + ((size_t)(bid * T_ + tc * TCH) * 16 + arow) * 256 + ahi * 8;
      v8hf aA[TCH], aB[TCH];
#pragma unroll
      for (int g = 0; g < 4; ++g)
        gld16(wfx_l + ((size_t)(0 * 16 + wid) * 4 + g) * 512 + laneoff, slot0 + g * 512);
#pragma unroll
      for (int rf = 0; rf < TCH; ++rf)
        aA[rf] = *(const v8hf*)(const void*)(abase + rf * 4096);

#pragma unroll
      for (int kc = 0; kc < 8; ++kc) {
        if (kc < 7) {
          u16* nd = ((kc + 1) & 1) ? slot1 : slot0;
#pragma unroll
          for (int g = 0; g < 4; ++g)
            gld16(wfx_l + ((size_t)((kc + 1) * 16 + wid) * 4 + g) * 512 + laneoff, nd + g * 512);
          if ((kc & 1) == 0) {
#pragma unroll
            for (int rf = 0; rf < TCH; ++rf)
              aB[rf] = *(const v8hf*)(const void*)(abase + rf * 4096 + (kc + 1) * 32);
          } else {
#pragma unroll
            for (int rf = 0; rf < TCH; ++rf)
              aA[rf] = *(const v8hf*)(const void*)(abase + rf * 4096 + (kc + 1) * 32);
          }
          asm volatile("s_waitcnt vmcnt(8)" ::: "memory");
        } else {
          asm volatile("s_waitcnt vmcnt(0)" ::: "memory");
        }
        __builtin_amdgcn_sched_barrier(0);
        const u16* wl = ((kc & 1) ? slot1 : slot0) + lane * 8;
#pragma unroll
        for (int g = 0; g < 4; ++g) {
          v8hf w = *(const v8hf*)(const void*)(wl + g * 512);
#pragma unroll
          for (int rf = 0; rf < TCH; ++rf)
            acc0[rf][g] = __builtin_amdgcn_mfma_f32_16x16x32_f16(
                ((kc & 1) ? aB[rf] : aA[rf]), w, acc0[rf][g], 0, 0, 0);
        }
      }
    }

#pragma unroll
    for (int g = 0; g < 4; ++g)
      gld16(wfh_l + ((size_t)(0 * 16 + wid) * 4 + g) * 512 + laneoff, slot0 + g * 512);
#pragma unroll
    for (int g = 0; g < 4; ++g)
      gld16(wfh_l + ((size_t)(1 * 16 + wid) * 4 + g) * 512 + laneoff, slot1 + g * 512);

    uint2 xr[TCH][4];
#pragma unroll
    for (int rf = 0; rf < TCH; ++rf)
#pragma unroll
      for (int g = 0; g < 4; ++g) {
        xr[rf][g].x = (u32)f2h(acc0[rf][g][0]) | ((u32)f2h(acc0[rf][g][1]) << 16);
        xr[rf][g].y = (u32)f2h(acc0[rf][g][2]) | ((u32)f2h(acc0[rf][g][3]) << 16);
      }

#pragma unroll
    for (int tl = 0; tl < TCH; ++tl) {
      const int t = tc * TCH + tl;
      f32x4 acc[4];
#pragma unroll
      for (int g = 0; g < 4; ++g) {
        acc[g][0] = h2f((u16)(xr[tl][g].x & 0xffff));
        acc[g][1] = h2f((u16)(xr[tl][g].x >> 16));
        acc[g][2] = h2f((u16)(xr[tl][g].y & 0xffff));
        acc[g][3] = h2f((u16)(xr[tl][g].y >> 16));
      }

#pragma unroll
      for (int kc = 0; kc < 8; ++kc) {
        if (kc < 7) asm volatile("s_waitcnt vmcnt(4)" ::: "memory");
        else        asm volatile("s_waitcnt vmcnt(0)" ::: "memory");
        __builtin_amdgcn_sched_barrier(0);

        v8hf a = *(const v8hf*)((const char*)Ah + arow * 512 +
                                ((kc * 64 + ahi * 16) ^ ((arow & 7) << 4)));
        const u16* wl = ((kc & 1) ? slot1 : slot0) + lane * 8;
#pragma unroll
        for (int g = 0; g < 4; ++g) {
          v8hf w = *(const v8hf*)(const void*)(wl + g * 512);
          acc[g] = __builtin_amdgcn_mfma_f32_16x16x32_f16(a, w, acc[g], 0, 0, 0);
        }
        if (kc < 6) {
          u16* nd = (kc & 1) ? slot1 : slot0;
#pragma unroll
          for (int g = 0; g < 4; ++g)
            gld16(wfh_l + ((size_t)((kc + 2) * 16 + wid) * 4 + g) * 512 + laneoff,
                  nd + g * 512);
        }
      }
      __syncthreads();

      if (tl + 1 < TCH) {
#pragma unroll
        for (int g = 0; g < 4; ++g)
          gld16(wfh_l + ((size_t)(0 * 16 + wid) * 4 + g) * 512 + laneoff, slot0 + g * 512);
#pragma unroll
        for (int g = 0; g < 4; ++g)
          gld16(wfh_l + ((size_t)(1 * 16 + wid) * 4 + g) * 512 + laneoff, slot1 + g * 512);
      }

      u16* sbase = seq + ((((size_t)bid * T_ + t) * 16) << 8) + j;
#pragma unroll
      for (int q = 0; q < 4; ++q) {
        int r = ahi * 4 + q;
        float cn = fsig(acc[1][q]) * c[q] + fsig(acc[0][q]) * ftanh(acc[2][q]);
        c[q] = cn;
        float h = fsig(acc[3][q]) * ftanh(cn);
        u16 hb = f2h(h);
        sbase[(size_t)r << 8] = hb;
        *(u16*)((char*)Ah + r * 512 + ((j * 2) ^ ((r & 7) << 4))) = hb;
      }
      __syncthreads();
    }
  }
}

// ---------------- tail (encoder / sample / decoder) ----------------
template <int N, int K, bool RELU>
__device__ __forceinline__ void dense(const float (*__restrict__ in)[512],
                                      float (*__restrict__ out)[512],
                                      const float* __restrict__ W,
                                      const float* __restrict__ bg, int tid) {
  for (int e = tid; e < 16 * N; e += 256) {
    int r = e / N, n = e - r * N;
    const float* wr = W + (size_t)n * K;
    const float* ar = in[r];
    float4 acc = {0.f, 0.f, 0.f, 0.f};
    for (int k = 0; k < K; k += 4) {
      float4 wv = *(const float4*)(wr + k);
      float4 av = *(const float4*)(ar + k);
      acc.x = fmaf(wv.x, av.x, acc.x);
      acc.y = fmaf(wv.y, av.y, acc.y);
      acc.z = fmaf(wv.z, av.z, acc.z);
      acc.w = fmaf(wv.w, av.w, acc.w);
    }
    float s = bg[n] + acc.x + acc.y + acc.z + acc.w;
    out[r][n] = RELU ? fmaxf(s, 0.f) : s;
  }
}

template <int K>
__device__ __forceinline__ float dotK(const float* __restrict__ a, const float* __restrict__ w) {
  float4 acc = {0.f, 0.f, 0.f, 0.f};
#pragma unroll
  for (int k = 0; k < K; k += 4) {
    float4 wv = *(const float4*)(w + k);
    float4 av = *(const float4*)(a + k);
    acc.x = fmaf(wv.x, av.x, acc.x);
    acc.y = fmaf(wv.y, av.y, acc.y);
    acc.z = fmaf(wv.z, av.z, acc.z);
    acc.w = fmaf(wv.w, av.w, acc.w);
  }
  return acc.x + acc.y + acc.z + acc.w;
}

struct TailArgs {
  const u16* seq;
  const float *ef1w, *ef1b, *ef2w, *ef2b;
  const float *mean_w, *mean_b, *logvar_w, *logvar_b;
  const float *scale_w, *scale_b, *shape_w, *shape_b;
  const float *df1w, *df1b, *df2w, *df2b, *outw, *outb, *finw, *finb;
  const float *pi, *eps, *u, *choice;
  float* out;
};

__global__ __launch_bounds__(256) void tail_kernel_v16(TailArgs A) {
  __shared__ float a0[16][512];
  __shared__ float a1[16][512];
  const int tid = threadIdx.x, bid = blockIdx.x;

  for (int e = tid; e < 16 * 256; e += 256) {
    int r = e >> 8, jj = e & 255;
    a0[r][jj] = h2f(A.seq[((((size_t)bid * T_ + (T_ - 1)) * 16 + r) << 8) + jj]);
  }
  __syncthreads();

  dense<128, 256, true>(a0, a1, A.ef1w, A.ef1b, tid); __syncthreads();
  dense<64, 128, true>(a1, a0, A.ef2w, A.ef2b, tid);  __syncthreads();

  const float pi = *A.pi;
  for (int e = tid; e < 16 * 64; e += 256) {
    int r = e >> 6, n = e & 63;
    size_t rg = (size_t)bid * 16 + r;
    float m  = dotK<64>(a0[r], A.mean_w   + n * 64) + A.mean_b[n];
    float lv = dotK<64>(a0[r], A.logvar_w + n * 64) + A.logvar_b[n];
    float sc = __expf(dotK<64>(a0[r], A.scale_w + n * 64) + A.scale_b[n]);
    float sh = dotK<64>(a0[r], A.shape_w + n * 64) + A.shape_b[n];
    A.out[196608 + rg * 64 + n] = m;
    A.out[327680 + rg * 64 + n] = lv;
    A.out[458752 + rg * 64 + n] = sc;
    A.out[589824 + rg * 64 + n] = sh;
    float zg = m + A.eps[rg * 64 + n] * __expf(0.5f * lv);
    float L  = log1pf(-A.u[rg * 64 + n]);
    float zp = sc / sh * (__expf(-sh * L) - 1.f);
    a1[r][n] = (A.choice[rg] < pi) ? zg : zp;
  }
  __syncthreads();

  dense<128, 64, true>(a1, a0, A.df1w, A.df1b, tid);   __syncthreads();
  dense<500, 128, true>(a0, a1, A.df2w, A.df2b, tid);  __syncthreads();
  dense<96, 500, false>(a1, a0, A.outw, A.outb, tid);  __syncthreads();
  dense<96, 96, false>(a0, a1, A.finw, A.finb, tid);   __syncthreads();

  for (int e = tid; e < 16 * FUT_; e += 256) {
    int r = e / FUT_, n = e - r * FUT_;
    A.out[((size_t)bid * 16 + r) * FUT_ + n] = a1[r][n];
  }
}

// ---------------- launch ----------------
extern "C" void kernel_launch(void* const* d_in, const int* in_sizes, int n_in,
                              void* d_out, int out_size, void* d_ws, size_t ws_size,
                              hipStream_t stream) {
  (void)in_sizes; (void)n_in; (void)out_size; (void)ws_size;

  const float* X      = (const float*)d_in[0];
  const float* Wih0   = (const float*)d_in[1];
  const float* Wih    = (const float*)d_in[2];
  const float* Whh    = (const float*)d_in[3];
  const float* b      = (const float*)d_in[4];
  const float* ef1w   = (const float*)d_in[5];
  const float* ef1b   = (const float*)d_in[6];
  const float* ef2w   = (const float*)d_in[7];
  const float* ef2b   = (const float*)d_in[8];
  const float* mean_w = (const float*)d_in[9];
  const float* mean_b = (const float*)d_in[10];
  const float* logvar_w = (const float*)d_in[11];
  const float* logvar_b = (const float*)d_in[12];
  const float* scale_w  = (const float*)d_in[13];
  const float* scale_b  = (const float*)d_in[14];
  const float* shape_w  = (const float*)d_in[15];
  const float* shape_b  = (const float*)d_in[16];
  const float* df1w   = (const float*)d_in[17];
  const float* df1b   = (const float*)d_in[18];
  const float* df2w   = (const float*)d_in[19];
  const float* df2b   = (const float*)d_in[20];
  const float* outw   = (const float*)d_in[21];
  const float* outb   = (const float*)d_in[22];
  const float* finw   = (const float*)d_in[23];
  const float* finb   = (const float*)d_in[24];
  const float* pi_g   = (const float*)d_in[25];
  const float* eps    = (const float*)d_in[26];
  const float* u      = (const float*)d_in[27];
  const float* choice = (const float*)d_in[28];

  float* out = (float*)d_out;
  u16* wfh = (u16*)((char*)d_ws + WFH_OFF);
  u16* wfx = (u16*)((char*)d_ws + WFX_OFF);
  u32* ctr = (u32*)((char*)d_ws + CTR_OFF);
  u16* seq = (u16*)((char*)d_ws + SEQ2_OFF);

  pack_weights_v16<<<2560, 256, 0, stream>>>(Wih0, Wih, Whh, wfh, wfx);
  hipMemsetAsync((void*)ctr, 0, 4096, stream);

  const float* Xa = X; u16* seqa = seq; const u16* wfha = wfh; const u16* wfxa = wfx;
  u32* ctra = ctr; const float* ba = b;
  void* params[] = {&Xa, &seqa, &wfha, &wfxa, &ctra, &ba};
  hipError_t e = hipLaunchCooperativeKernel((void*)lstm_coop_v16, dim3(256), dim3(1024),
                                            params, 0, stream);
  if (e != hipSuccess) {
    // fallback: proven v14 path (repack in v14 layout, same regions)
    pack_weights_v14<<<2560, 256, 0, stream>>>(Wih0, Wih, Whh, wfh, wfx);
    lstm_layer_v14<true><<<NBLK, 1024, 0, stream>>>(X, seq, wfx, wfh, b);
    for (int l = 1; l < NL_; ++l)
      lstm_layer_v14<false><<<NBLK, 1024, 0, stream>>>(nullptr, seq,
          wfx + (size_t)l * WFL, wfh + (size_t)l * WFL, b + l * 1024);
  }

  TailArgs A;
  A.seq = seq;
  A.ef1w = ef1w; A.ef1b = ef1b; A.ef2w = ef2w; A.ef2b = ef2b;
  A.mean_w = mean_w; A.mean_b = mean_b; A.logvar_w = logvar_w; A.logvar_b = logvar_b;
  A.scale_w = scale_w; A.scale_b = scale_b; A.shape_w = shape_w; A.shape_b = shape_b;
  A.df1w = df1w; A.df1b = df1b; A.df2w = df2w; A.df2b = df2b;
  A.outw = outw; A.outb = outb; A.finw = finw; A.finb = finb;
  A.pi = pi_g; A.eps = eps; A.u = u; A.choice = choice;
  A.out = out;
  tail_kernel_v16<<<NBLK, 256, 0, stream>>>(A);
}